// Round 6
// baseline (122.168 us; speedup 1.0000x reference)
//
#include <hip/hip_runtime.h>
#include <math.h>

typedef float f32x4 __attribute__((ext_vector_type(4)));
typedef __bf16 bf16x8 __attribute__((ext_vector_type(8)));

// ---------------------------------------------------------------------------
// CSR row offsets from sorted self_fea_idx. row_start[N] = M.
// ---------------------------------------------------------------------------
__global__ void build_row_start(const int* __restrict__ self_idx,
                                int* __restrict__ row_start, int M, int N) {
  int i = blockIdx.x * blockDim.x + threadIdx.x;
  if (i >= M) return;
  int cur = self_idx[i];
  int prev = (i == 0) ? -1 : self_idx[i - 1];
  for (int j = prev + 1; j <= cur; ++j) row_start[j] = i;
  if (i == M - 1) {
    for (int j = cur + 1; j <= N; ++j) row_start[j] = M;
  }
}

// ---------------------------------------------------------------------------
// Phase A: per-atom precompute of layer-1 halves (bf16 in ws) and a
// B-frag-packed copy of W2.
//   U'[a][d] = sum_k X[a][k]*W1[k][d] + b1[d]
//   Y [a][d] = sum_k X[a][k]*W1[64+k][d]
//   W2pack[(ks*4+c)*64 + lane][0..7] = W2[32ks+8g+j][16c+r16], lane=16g+r16
// ---------------------------------------------------------------------------
__global__ __launch_bounds__(256, 2)
void precompute_uy(const float* __restrict__ atom_fea,
                   const float* __restrict__ W1,
                   const float* __restrict__ b1,
                   const float* __restrict__ W2,
                   __bf16* __restrict__ Ub, __bf16* __restrict__ Yb,
                   __bf16* __restrict__ W2pack, int N) {
  const int lane = threadIdx.x & 63;
  const int r16 = lane & 15, g = lane >> 4;
  const int wid = (blockIdx.x * blockDim.x + threadIdx.x) >> 6;
  const int nw = (gridDim.x * blockDim.x) >> 6;

  if (wid == 0) {  // pack W2 into B-frag order (8 KB, once)
#pragma unroll
    for (int ks = 0; ks < 2; ++ks)
#pragma unroll
      for (int c = 0; c < 4; ++c) {
        bf16x8 t;
#pragma unroll
        for (int jj = 0; jj < 8; ++jj)
          t[jj] = (__bf16)W2[(size_t)(32 * ks + 8 * g + jj) * 64 + 16 * c + r16];
        *(bf16x8*)(W2pack + ((size_t)(ks * 4 + c) * 64 + lane) * 8) = t;
      }
  }

  bf16x8 wt[2][4], wb[2][4];
#pragma unroll
  for (int ks = 0; ks < 2; ++ks)
#pragma unroll
    for (int c = 0; c < 4; ++c) {
      bf16x8 t, b;
#pragma unroll
      for (int jj = 0; jj < 8; ++jj) {
        int k = 32 * ks + 8 * g + jj;
        t[jj] = (__bf16)W1[(size_t)k * 64 + 16 * c + r16];
        b[jj] = (__bf16)W1[(size_t)(64 + k) * 64 + 16 * c + r16];
      }
      wt[ks][c] = t; wb[ks][c] = b;
    }
  float b1c[4];
#pragma unroll
  for (int c = 0; c < 4; ++c) b1c[c] = b1[16 * c + r16];

  const int nTiles = (N + 15) >> 4;
  for (int tile = wid; tile < nTiles; tile += nw) {
    const int a0 = tile * 16;
    int arow = a0 + r16; if (arow >= N) arow = N - 1;

    bf16x8 af[2];
#pragma unroll
    for (int ks = 0; ks < 2; ++ks) {
      const float* p = atom_fea + (size_t)arow * 64 + 32 * ks + 8 * g;
      f32x4 x0 = *(const f32x4*)p;
      f32x4 x1 = *(const f32x4*)(p + 4);
      bf16x8 a;
#pragma unroll
      for (int jj = 0; jj < 4; ++jj) { a[jj] = (__bf16)x0[jj]; a[4 + jj] = (__bf16)x1[jj]; }
      af[ks] = a;
    }

    f32x4 uacc[4], yacc[4];
#pragma unroll
    for (int c = 0; c < 4; ++c) { uacc[c] = (f32x4)0.0f; yacc[c] = (f32x4)0.0f; }
#pragma unroll
    for (int ks = 0; ks < 2; ++ks)
#pragma unroll
      for (int c = 0; c < 4; ++c) {
        uacc[c] = __builtin_amdgcn_mfma_f32_16x16x32_bf16(af[ks], wt[ks][c], uacc[c], 0, 0, 0);
        yacc[c] = __builtin_amdgcn_mfma_f32_16x16x32_bf16(af[ks], wb[ks][c], yacc[c], 0, 0, 0);
      }

#pragma unroll
    for (int c = 0; c < 4; ++c)
#pragma unroll
      for (int j = 0; j < 4; ++j) {
        int row = a0 + 4 * g + j;
        if (row < N) {
          Ub[(size_t)row * 64 + 16 * c + r16] = (__bf16)(uacc[c][j] + b1c[c]);
          Yb[(size_t)row * 64 + 16 * c + r16] = (__bf16)yacc[c][j];
        }
      }
  }
}

// ---------------------------------------------------------------------------
// Main fused kernel, v3: TWO independent segment streams per wave (ILP).
// pooled = (sum_e w_e H_e) @ W2 + (sum_e w_e) b2,  w_e = aw*exp(H_e.wg2+bgp)
// Per 16-edge tile: gather Y rows, H in f32 regs, gate dot + 2 shfl, exp,
// z-FMA. The two streams' load->compute chains interleave so stream B's
// memory latency hides under stream A's compute and vice versa.
// Finalize (per pair): shared W2-frag loads, 8+8 MFMA, shfl reduces, store.
// ---------------------------------------------------------------------------
__global__ __launch_bounds__(64, 3)
void fused_pool(const float* __restrict__ atom_w,
                const float* __restrict__ atom_fea,
                const int* __restrict__ nbr_idx,
                const float* __restrict__ W2,
                const float* __restrict__ b2,
                const float* __restrict__ Wg,
                const float* __restrict__ bg,
                const int* __restrict__ row_start,
                const __bf16* __restrict__ Ub,
                const __bf16* __restrict__ Yb,
                const __bf16* __restrict__ W2pack,
                float* __restrict__ out, int N) {
  const int lane = threadIdx.x & 63;
  const int r16 = lane & 15, g = lane >> 4;

  // wg2[k] = sum_d W2[k][d]*Wg[d]  (lane holds k = lane)
  float wgl = 0.f;
  {
    const float* w2row = W2 + (size_t)lane * 64;
#pragma unroll
    for (int d = 0; d < 64; ++d) wgl = fmaf(w2row[d], Wg[d], wgl);
  }
  // distribute wg2 into this lane's A-frag k-slots: k = 32ks + 8g + jj
  float wgsl[16];
#pragma unroll
  for (int ks = 0; ks < 2; ++ks)
#pragma unroll
    for (int jj = 0; jj < 8; ++jj)
      wgsl[ks * 8 + jj] = __shfl(wgl, 32 * ks + 8 * g + jj);

  // bgp = bg + sum_d b2[d]*Wg[d]
  float tb = b2[lane] * Wg[lane];
#pragma unroll
  for (int off = 1; off < 64; off <<= 1) tb += __shfl_xor(tb, off);
  const float bgp = bg[0] + tb;
  const float b2l = b2[lane];

  const int pstride = 2 * gridDim.x;
  for (int p0 = 2 * blockIdx.x; p0 < N; p0 += pstride) {
    const int sA = p0;
    const int sB = p0 + 1;
    const bool hasB = sB < N;

    const int startA = row_start[sA];
    const int endA = row_start[sA + 1];
    const int startB = hasB ? row_start[sB] : 0;
    const int endB = hasB ? row_start[sB + 1] : 0;

    float ufA[16], ufB[16];
    {
      const bf16x8 a0 = *(const bf16x8*)(Ub + (size_t)sA * 64 + 8 * g);
      const bf16x8 a1 = *(const bf16x8*)(Ub + (size_t)sA * 64 + 32 + 8 * g);
      const bf16x8 c0 = hasB ? *(const bf16x8*)(Ub + (size_t)sB * 64 + 8 * g) : a0;
      const bf16x8 c1 = hasB ? *(const bf16x8*)(Ub + (size_t)sB * 64 + 32 + 8 * g) : a1;
#pragma unroll
      for (int jj = 0; jj < 8; ++jj) {
        ufA[jj] = (float)a0[jj]; ufA[8 + jj] = (float)a1[jj];
        ufB[jj] = (float)c0[jj]; ufB[8 + jj] = (float)c1[jj];
      }
    }

    float zA[16], zB[16];
#pragma unroll
    for (int k = 0; k < 16; ++k) { zA[k] = 0.f; zB[k] = 0.f; }
    float wsumA = 0.f, wsumB = 0.f;

    const int nTA = (endA - startA + 15) >> 4;
    const int nTB = (endB - startB + 15) >> 4;
    const int nT = nTA > nTB ? nTA : nTB;

    for (int t = 0; t < nT; ++t) {
      const int baseA = startA + 16 * t;
      const int baseB = startB + 16 * t;
      const bool actA = baseA < endA;
      const bool actB = hasB && baseB < endB;

      // ---- issue loads for both streams up front ----
      int nbA = 0; bf16x8 yA0 = {}, yA1 = {}; float awA = 0.f; bool vA = false;
      int nbB = 0; bf16x8 yB0 = {}, yB1 = {}; float awB = 0.f; bool vB = false;
      if (actA) {
        const int e = baseA + r16; vA = e < endA;
        nbA = vA ? nbr_idx[e] : 0;
        const __bf16* yr = Yb + ((size_t)nbA << 6);
        yA0 = *(const bf16x8*)(yr + 8 * g);
        yA1 = *(const bf16x8*)(yr + 32 + 8 * g);
        awA = atom_w[nbA];
      }
      if (actB) {
        const int e = baseB + r16; vB = e < endB;
        nbB = vB ? nbr_idx[e] : 0;
        const __bf16* yr = Yb + ((size_t)nbB << 6);
        yB0 = *(const bf16x8*)(yr + 8 * g);
        yB1 = *(const bf16x8*)(yr + 32 + 8 * g);
        awB = atom_w[nbB];
      }

      // ---- compute stream A ----
      if (actA) {
        float hf[16];
#pragma unroll
        for (int jj = 0; jj < 8; ++jj) {
          float a = ufA[jj] + (float)yA0[jj];
          float b = ufA[8 + jj] + (float)yA1[jj];
          hf[jj] = fmaxf(a, 0.01f * a);
          hf[8 + jj] = fmaxf(b, 0.01f * b);
        }
        float pacc = 0.f;
#pragma unroll
        for (int i = 0; i < 16; ++i) pacc = fmaf(hf[i], wgsl[i], pacc);
        pacc += __shfl_xor(pacc, 16);
        pacc += __shfl_xor(pacc, 32);
        const float w = vA ? awA * __expf(pacc + bgp) : 0.f;
        wsumA += w;
#pragma unroll
        for (int k = 0; k < 16; ++k) zA[k] = fmaf(w, hf[k], zA[k]);
      }
      // ---- compute stream B ----
      if (actB) {
        float hf[16];
#pragma unroll
        for (int jj = 0; jj < 8; ++jj) {
          float a = ufB[jj] + (float)yB0[jj];
          float b = ufB[8 + jj] + (float)yB1[jj];
          hf[jj] = fmaxf(a, 0.01f * a);
          hf[8 + jj] = fmaxf(b, 0.01f * b);
        }
        float pacc = 0.f;
#pragma unroll
        for (int i = 0; i < 16; ++i) pacc = fmaf(hf[i], wgsl[i], pacc);
        pacc += __shfl_xor(pacc, 16);
        pacc += __shfl_xor(pacc, 32);
        const float w = vB ? awB * __expf(pacc + bgp) : 0.f;
        wsumB += w;
#pragma unroll
        for (int k = 0; k < 16; ++k) zB[k] = fmaf(w, hf[k], zB[k]);
      }
    }

    // ---- finalize both segments; W2 frags loaded once ----
    const float xrA = atom_fea[(size_t)sA * 64 + lane];
    const float xrB = hasB ? atom_fea[(size_t)sB * 64 + lane] : 0.f;

    bf16x8 zfA0, zfA1, zfB0, zfB1;
#pragma unroll
    for (int jj = 0; jj < 8; ++jj) {
      zfA0[jj] = (__bf16)zA[jj]; zfA1[jj] = (__bf16)zA[8 + jj];
      zfB0[jj] = (__bf16)zB[jj]; zfB1[jj] = (__bf16)zB[8 + jj];
    }

    f32x4 fA[4], fB[4];
#pragma unroll
    for (int c = 0; c < 4; ++c) { fA[c] = (f32x4)0.0f; fB[c] = (f32x4)0.0f; }
#pragma unroll
    for (int c = 0; c < 4; ++c) {
      const bf16x8 wf0 = *(const bf16x8*)(W2pack + ((size_t)(0 * 4 + c) * 64 + lane) * 8);
      const bf16x8 wf1 = *(const bf16x8*)(W2pack + ((size_t)(1 * 4 + c) * 64 + lane) * 8);
      fA[c] = __builtin_amdgcn_mfma_f32_16x16x32_bf16(zfA0, wf0, fA[c], 0, 0, 0);
      fA[c] = __builtin_amdgcn_mfma_f32_16x16x32_bf16(zfA1, wf1, fA[c], 0, 0, 0);
      fB[c] = __builtin_amdgcn_mfma_f32_16x16x32_bf16(zfB0, wf0, fB[c], 0, 0, 0);
      fB[c] = __builtin_amdgcn_mfma_f32_16x16x32_bf16(zfB1, wf1, fB[c], 0, 0, 0);
    }

    // reduce C rows (16 z-partial rows) -> pooled numerator per dim
    float avA[4], avB[4];
#pragma unroll
    for (int c = 0; c < 4; ++c) {
      float a = (fA[c][0] + fA[c][1]) + (fA[c][2] + fA[c][3]);
      float b = (fB[c][0] + fB[c][1]) + (fB[c][2] + fB[c][3]);
      a += __shfl_xor(a, 16); b += __shfl_xor(b, 16);
      a += __shfl_xor(a, 32); b += __shfl_xor(b, 32);
      avA[c] = a; avB[c] = b;
    }
    float ssA = wsumA, ssB = wsumB;
#pragma unroll
    for (int off = 1; off < 16; off <<= 1) {
      ssA += __shfl_xor(ssA, off);
      ssB += __shfl_xor(ssB, off);
    }

    float valA = avA[0];
    valA = (g == 1) ? avA[1] : valA;
    valA = (g == 2) ? avA[2] : valA;
    valA = (g == 3) ? avA[3] : valA;
    valA = fmaf(ssA, b2l, valA);
    out[(size_t)sA * 64 + lane] = valA / (ssA + 1e-13f) + xrA;

    if (hasB) {
      float valB = avB[0];
      valB = (g == 1) ? avB[1] : valB;
      valB = (g == 2) ? avB[2] : valB;
      valB = (g == 3) ? avB[3] : valB;
      valB = fmaf(ssB, b2l, valB);
      out[(size_t)sB * 64 + lane] = valB / (ssB + 1e-13f) + xrB;
    }
  }
}

extern "C" void kernel_launch(void* const* d_in, const int* in_sizes, int n_in,
                              void* d_out, int out_size, void* d_ws, size_t ws_size,
                              hipStream_t stream) {
  const float* atom_w   = (const float*)d_in[0];
  const float* atom_fea = (const float*)d_in[1];
  const int*   self_idx = (const int*)d_in[2];
  const int*   nbr_idx  = (const int*)d_in[3];
  const float* W1 = (const float*)d_in[4];
  const float* b1 = (const float*)d_in[5];
  const float* W2 = (const float*)d_in[6];
  const float* b2 = (const float*)d_in[7];
  const float* Wg = (const float*)d_in[8];
  const float* bg = (const float*)d_in[9];
  float* out = (float*)d_out;

  const int N = in_sizes[0];   // atom_weights is (N,1)
  const int M = in_sizes[2];   // self_fea_idx is (M,)

  char* ws = (char*)d_ws;
  int* row_start = (int*)ws;
  size_t off = ((size_t)(N + 1) * sizeof(int) + 255) & ~(size_t)255;
  __bf16* W2pack = (__bf16*)(ws + off);
  __bf16* Ub = W2pack + 8 * 64 * 8;          // 8KB pack region
  __bf16* Yb = Ub + (size_t)N * 64;

  hipLaunchKernelGGL(build_row_start, dim3((M + 255) / 256), dim3(256), 0,
                     stream, self_idx, row_start, M, N);
  hipLaunchKernelGGL(precompute_uy, dim3(512), dim3(256), 0, stream,
                     atom_fea, W1, b1, W2, Ub, Yb, W2pack, N);
  hipLaunchKernelGGL(fused_pool, dim3(8192), dim3(64), 0, stream,
                     atom_w, atom_fea, nbr_idx, W2, b2, Wg, bg,
                     row_start, Ub, Yb, W2pack, out, N);
}